// Round 5
// baseline (100.702 us; speedup 1.0000x reference)
//
#include <hip/hip_runtime.h>
#include <hip/hip_bf16.h>

// Problem constants (from reference)
#define BATCH   8
#define MROWS   2048      // C*P = 4*512
#define DIM_Z   512
#define DIM_G   1024
#define EDIM    128
#define EPS     1e-6f

typedef unsigned short u16;
typedef unsigned int   u32;
typedef __attribute__((ext_vector_type(8))) short bf16x8;
typedef __attribute__((ext_vector_type(4))) float f32x4;

// f32 -> bf16 round-to-nearest-even (bit trick; inputs are finite)
__device__ __forceinline__ u16 f2b(float f) {
    u32 x = __float_as_uint(f);
    u32 r = x + 0x7fffu + ((x >> 16) & 1u);
    return (u16)(r >> 16);
}

// ---- kernel 1: u = a_emb @ Wu^T, v = a_emb @ Wv^T (coalesced) ----
__global__ void uv_kernel(const float* __restrict__ emb, const int* __restrict__ idx,
                          const float* __restrict__ Wu, const float* __restrict__ Wv,
                          float* __restrict__ u, float* __restrict__ v) {
    __shared__ float a[EDIM];
    int b = blockIdx.y;
    int t = threadIdx.x;
    if (t < EDIM) a[t] = emb[(size_t)idx[b] * EDIM + t];
    __syncthreads();
    int tx = t & 31, ty = t >> 5;
    int oBase = blockIdx.x * 256;
    for (int o0 = 0; o0 < 256; o0 += 8) {
        int o = oBase + o0 + ty;
        const float* wrow = (o < DIM_G) ? (Wu + (size_t)o * EDIM)
                                        : (Wv + (size_t)(o - DIM_G) * EDIM);
        float s = 0.f;
#pragma unroll
        for (int q = 0; q < 4; ++q) s += a[q * 32 + tx] * wrow[q * 32 + tx];
        s += __shfl_xor(s, 1, 64);
        s += __shfl_xor(s, 2, 64);
        s += __shfl_xor(s, 4, 64);
        s += __shfl_xor(s, 8, 64);
        s += __shfl_xor(s, 16, 64);
        if (tx == 0) {
            if (o < DIM_G) u[b * DIM_G + o] = s;
            else           v[b * DIM_Z + (o - DIM_G)] = s;
        }
    }
}

// -- kernel 2: W[b,g,d] = W_base + u*v -> bf16 (+ transposed WT) --
// 1D grid 4096, b = h&7 -> same-batch tiles on one XCD so W/WT stay dirty in
// that XCD's L2 for the fused GEMM to hit.
__global__ void wpack_kernel(const float* __restrict__ Wbase,
                             const float* __restrict__ u, const float* __restrict__ v,
                             u16* __restrict__ W, u16* __restrict__ WT) {
    __shared__ u16 tile[32][33];
    int h = blockIdx.x;
    int b = h & 7, t8 = h >> 3;          // t8 in [0,512)
    int d0 = (t8 & 15) * 32, g0 = (t8 >> 4) * 32;
    int tx = threadIdx.x, ty = threadIdx.y;
    float vb = v[b * DIM_Z + d0 + tx];
#pragma unroll
    for (int j = 0; j < 4; ++j) {
        int g = g0 + ty + j * 8;
        u16 h16 = f2b(Wbase[(size_t)g * DIM_Z + d0 + tx] + u[b * DIM_G + g] * vb);
        W[((size_t)b * DIM_G + g) * DIM_Z + d0 + tx] = h16;
        tile[ty + j * 8][tx] = h16;
    }
    __syncthreads();
#pragma unroll
    for (int j = 0; j < 4; ++j)
        WT[((size_t)b * DIM_Z + d0 + ty + j * 8) * DIM_G + g0 + tx] =
            tile[tx][ty + j * 8];
}

// ---------------- fused double-GEMM ----------------
// Block = (batch b = h&7 -> XCD b, 64-row m-strip). 512 threads / 8 waves.
// Phase 0: qz[64][512] f32 -> bf16 LDS (XOR-swizzled), once.
// Phase 1: qg = relu(qz @ W^T): acc[4][8] f32x4 = 64m x 128g per wave (g-slice),
//          A-frags ds_read_b128 from LDS, B-frags bf16x8 direct from W (L2).
//          NO barriers in the K-loop.
// Transition: relu + rowsum (shfl + LDS partials), qg -> bf16 LDS [64][1024]
//          (overlays qz region), inv[64] in LDS. 3 barriers total.
// Phase 2: out = (qg @ WT^T) * inv: acc2[4][4] = 64m x 64d per wave (d-slice),
//          A-frags from qg LDS, B-frags direct from WT (L2). No barriers.
__global__ __launch_bounds__(512, 2)
void fused_gemm(const float* __restrict__ qz, const u16* __restrict__ W,
                const u16* __restrict__ WT, float* __restrict__ out) {
    __shared__ u16 qgs[64 * 1024];    // 128 KB; first 64 KB doubles as qz tile
    __shared__ float part_l[8][64];
    __shared__ float inv_l[64];

    int h = blockIdx.x;
    int b = h & 7;
    int m0 = (h >> 3) * 64;
    const float* qzb = qz + ((size_t)b * MROWS + m0) * DIM_Z;
    const u16* Wb  = W  + (size_t)b * DIM_G * DIM_Z;
    const u16* WTb = WT + (size_t)b * DIM_Z * DIM_G;

    int tid = threadIdx.x;
    int lane = tid & 63, w = tid >> 6;
    int lr = lane & 15, lg = lane >> 4;

    // ---- phase 0: stage qz strip, swizzle byte ^= (m&7)<<4 ----
#pragma unroll
    for (int i = 0; i < 8; ++i) {
        int c = i * 512 + tid;            // 8-elem chunk id; 4096 chunks
        int m = c >> 6, k8 = c & 63;
        const float4* s = (const float4*)(qzb + (size_t)m * DIM_Z + k8 * 8);
        float4 f0 = s[0], f1 = s[1];
        union { u16 us[8]; uint4 v; } o;
        o.us[0] = f2b(f0.x); o.us[1] = f2b(f0.y); o.us[2] = f2b(f0.z); o.us[3] = f2b(f0.w);
        o.us[4] = f2b(f1.x); o.us[5] = f2b(f1.y); o.us[6] = f2b(f1.z); o.us[7] = f2b(f1.w);
        *(uint4*)((char*)qgs + ((m * 1024 + k8 * 16) ^ ((m & 7) << 4))) = o.v;
    }
    __syncthreads();

    // ---- phase 1: qg acc in registers ----
    f32x4 acc[4][8] = {};
    int gw = w * 128;
#pragma unroll 2
    for (int kt = 0; kt < DIM_Z; kt += 32) {
        bf16x8 af[4], bfr[8];
#pragma unroll
        for (int mi = 0; mi < 4; ++mi)
            af[mi] = *(const bf16x8*)((char*)qgs +
                (((mi * 16 + lr) * 1024 + (kt + lg * 8) * 2) ^ ((lr & 7) << 4)));
#pragma unroll
        for (int gi = 0; gi < 8; ++gi)
            bfr[gi] = *(const bf16x8*)(Wb + (size_t)(gw + gi * 16 + lr) * DIM_Z + kt + lg * 8);
#pragma unroll
        for (int mi = 0; mi < 4; ++mi)
#pragma unroll
            for (int gi = 0; gi < 8; ++gi)
                acc[mi][gi] = __builtin_amdgcn_mfma_f32_16x16x32_bf16(
                    af[mi], bfr[gi], acc[mi][gi], 0, 0, 0);
    }

    // ---- transition: relu, row partial sums, qg -> LDS bf16 ----
#pragma unroll
    for (int mi = 0; mi < 4; ++mi)
#pragma unroll
        for (int r = 0; r < 4; ++r) {
            float s = 0.f;
#pragma unroll
            for (int gi = 0; gi < 8; ++gi) {
                float t = fmaxf(acc[mi][gi][r], 0.f);
                acc[mi][gi][r] = t;
                s += t;
            }
            s += __shfl_xor(s, 1, 64);
            s += __shfl_xor(s, 2, 64);
            s += __shfl_xor(s, 4, 64);
            s += __shfl_xor(s, 8, 64);
            if (lr == 0) part_l[w][mi * 16 + lg * 4 + r] = s;
        }
    __syncthreads();   // all phase-1 LDS reads done; partials visible

    if (tid < 64) {
        float s = 0.f;
#pragma unroll
        for (int w2 = 0; w2 < 8; ++w2) s += part_l[w2][tid];
        inv_l[tid] = 1.f / fmaxf(s, EPS);
    }
    // qg[m][g] bf16, row-major [64][1024], byte ^= (m&7)<<4 (overlays qz region)
#pragma unroll
    for (int mi = 0; mi < 4; ++mi)
#pragma unroll
        for (int gi = 0; gi < 8; ++gi)
#pragma unroll
            for (int r = 0; r < 4; ++r) {
                int m = mi * 16 + lg * 4 + r;
                int g = gw + gi * 16 + lr;
                *(u16*)((char*)qgs + ((m * 2048 + g * 2) ^ ((m & 7) << 4))) =
                    f2b(acc[mi][gi][r]);
            }
    __syncthreads();   // qg + inv complete

    // ---- phase 2: out = qg @ WT^T * inv ----
    f32x4 acc2[4][4] = {};
    int dw = w * 64;
#pragma unroll 2
    for (int kt = 0; kt < DIM_G; kt += 32) {
        bf16x8 af[4], bfr[4];
#pragma unroll
        for (int mi = 0; mi < 4; ++mi)
            af[mi] = *(const bf16x8*)((char*)qgs +
                (((mi * 16 + lr) * 2048 + (kt + lg * 8) * 2) ^ ((lr & 7) << 4)));
#pragma unroll
        for (int di = 0; di < 4; ++di)
            bfr[di] = *(const bf16x8*)(WTb + (size_t)(dw + di * 16 + lr) * DIM_G + kt + lg * 8);
#pragma unroll
        for (int mi = 0; mi < 4; ++mi)
#pragma unroll
            for (int di = 0; di < 4; ++di)
                acc2[mi][di] = __builtin_amdgcn_mfma_f32_16x16x32_bf16(
                    af[mi], bfr[di], acc2[mi][di], 0, 0, 0);
    }

    float* ob = out + ((size_t)b * MROWS + m0) * DIM_Z;
#pragma unroll
    for (int mi = 0; mi < 4; ++mi)
#pragma unroll
        for (int r = 0; r < 4; ++r) {
            int m = mi * 16 + lg * 4 + r;
            float iv = inv_l[m];
#pragma unroll
            for (int di = 0; di < 4; ++di)
                ob[(size_t)m * DIM_Z + dw + di * 16 + lr] = acc2[mi][di][r] * iv;
        }
}

extern "C" void kernel_launch(void* const* d_in, const int* in_sizes, int n_in,
                              void* d_out, int out_size, void* d_ws, size_t ws_size,
                              hipStream_t stream) {
    const float* qz    = (const float*)d_in[0];
    const int*   attr  = (const int*)d_in[1];
    const float* Wbase = (const float*)d_in[2];
    const float* emb   = (const float*)d_in[3];
    const float* Wu    = (const float*)d_in[4];
    const float* Wv    = (const float*)d_in[5];
    float* out = (float*)d_out;

    // workspace carve-up (all 256B aligned)
    char* ws = (char*)d_ws;
    size_t off = 0;
    auto alloc = [&](size_t bytes) -> void* {
        void* p = ws + off;
        off = (off + bytes + 255) & ~(size_t)255;
        return p;
    };
    float* u  = (float*)alloc((size_t)BATCH * DIM_G * 4);
    float* v  = (float*)alloc((size_t)BATCH * DIM_Z * 4);
    u16*   W  = (u16*)  alloc((size_t)BATCH * DIM_G * DIM_Z * 2);
    u16*   WT = (u16*)  alloc((size_t)BATCH * DIM_G * DIM_Z * 2);
    if (off > ws_size) return;  // fail loudly (zero output) rather than corrupt

    uv_kernel<<<dim3(6, BATCH), dim3(256), 0, stream>>>(emb, attr, Wu, Wv, u, v);

    wpack_kernel<<<dim3(4096), dim3(32, 8), 0, stream>>>(Wbase, u, v, W, WT);

    // fused: 32 m-strips x 8 batches = 256 blocks (1 per CU; batch = XCD)
    fused_gemm<<<dim3(256), dim3(512), 0, stream>>>(qz, W, WT, out);
}

// Round 6
// 89.524 us; speedup vs baseline: 1.1249x; 1.1249x over previous
//
#include <hip/hip_runtime.h>
#include <hip/hip_bf16.h>

// Problem constants (from reference)
#define BATCH   8
#define MROWS   2048      // C*P = 4*512
#define DIM_Z   512
#define DIM_G   1024
#define EDIM    128
#define EPS     1e-6f
#define BK      64        // GEMM K-step

typedef unsigned short u16;
typedef unsigned int   u32;
typedef __attribute__((ext_vector_type(8))) short bf16x8;
typedef __attribute__((ext_vector_type(4))) float f32x4;

// f32 -> bf16 round-to-nearest-even (bit trick; inputs are finite)
__device__ __forceinline__ u16 f2b(float f) {
    u32 x = __float_as_uint(f);
    u32 r = x + 0x7fffu + ((x >> 16) & 1u);
    return (u16)(r >> 16);
}

// async global->LDS, 16B per lane, dest = wave-uniform base + lane*16
#define GLD16(gsrc, ldst) __builtin_amdgcn_global_load_lds( \
    (const __attribute__((address_space(1))) unsigned int*)(gsrc), \
    (__attribute__((address_space(3))) unsigned int*)(ldst), 16, 0, 0)

// ---- kernel 1: u = a_emb @ Wu^T, v = a_emb @ Wv^T (coalesced), + zero rsum ----
__global__ void uv_kernel(const float* __restrict__ emb, const int* __restrict__ idx,
                          const float* __restrict__ Wu, const float* __restrict__ Wv,
                          float* __restrict__ u, float* __restrict__ v,
                          float* __restrict__ rsum) {
    __shared__ float a[EDIM];
    int b = blockIdx.y;
    int t = threadIdx.x;
    if (blockIdx.x == 0)   // zero rsum[b] (runs before GEMM1 in stream order)
        for (int i = t; i < MROWS; i += 256) rsum[(size_t)b * MROWS + i] = 0.f;
    if (t < EDIM) a[t] = emb[(size_t)idx[b] * EDIM + t];
    __syncthreads();
    int tx = t & 31, ty = t >> 5;
    int oBase = blockIdx.x * 256;
    for (int o0 = 0; o0 < 256; o0 += 8) {
        int o = oBase + o0 + ty;
        const float* wrow = (o < DIM_G) ? (Wu + (size_t)o * EDIM)
                                        : (Wv + (size_t)(o - DIM_G) * EDIM);
        float s = 0.f;
#pragma unroll
        for (int q = 0; q < 4; ++q) s += a[q * 32 + tx] * wrow[q * 32 + tx];
        s += __shfl_xor(s, 1, 64);
        s += __shfl_xor(s, 2, 64);
        s += __shfl_xor(s, 4, 64);
        s += __shfl_xor(s, 8, 64);
        s += __shfl_xor(s, 16, 64);
        if (tx == 0) {
            if (o < DIM_G) u[b * DIM_G + o] = s;
            else           v[b * DIM_Z + (o - DIM_G)] = s;
        }
    }
}

// -- kernel 2: W[b,g,d] = W_base + u*v -> bf16 (+ transposed WT) --
// 1D grid 4096, b = h&7 -> same-batch tiles on one XCD so W/WT stay dirty in
// that XCD's L2 for the GEMMs (which use the same b = h&7 mapping) to hit.
__global__ void wpack_kernel(const float* __restrict__ Wbase,
                             const float* __restrict__ u, const float* __restrict__ v,
                             u16* __restrict__ W, u16* __restrict__ WT) {
    __shared__ u16 tile[32][33];
    int h = blockIdx.x;
    int b = h & 7, t8 = h >> 3;          // t8 in [0,512)
    int d0 = (t8 & 15) * 32, g0 = (t8 >> 4) * 32;
    int tx = threadIdx.x, ty = threadIdx.y;
    float vb = v[b * DIM_Z + d0 + tx];
#pragma unroll
    for (int j = 0; j < 4; ++j) {
        int g = g0 + ty + j * 8;
        u16 h16 = f2b(Wbase[(size_t)g * DIM_Z + d0 + tx] + u[b * DIM_G + g] * vb);
        W[((size_t)b * DIM_G + g) * DIM_Z + d0 + tx] = h16;
        tile[ty + j * 8][tx] = h16;
    }
    __syncthreads();
#pragma unroll
    for (int j = 0; j < 4; ++j)
        WT[((size_t)b * DIM_Z + d0 + ty + j * 8) * DIM_G + g0 + tx] =
            tile[tx][ty + j * 8];
}

// ---------------- GEMM: C[m,n] = sum_k A[m,k] * Bt[n,k], per-batch ----------------
// T3 minimum-2-phase pipeline (guide §5.5): double-buffered LDS; tile t+1's
// loads issued BEFORE computing tile t; ONE __syncthreads per K-step (its
// vmcnt(0) drain waits on loads that had the whole compute phase in flight).
// B (and A when bf16) staged via global_load_lds (linear LDS dest, source chunk
// pre-swizzled c^(row&7); reads apply the same XOR — rule #21). A-f32 path
// (fused qz cast): f32 loads at iter top, cvt+swizzled ds_write AFTER the MFMAs.
// 1D grid, XCD decode: b = h&7 (batch->XCD, W L2-resident), j = h>>3 n-fastest.
// 128x128 tile, 4 waves (2x2), each wave 64x64 via 4x4 mfma_16x16x32 frags.
// EPI=0: relu -> bf16 store (qg) + per-row partial-sum atomicAdd into rsum.
// EPI=1: scale by 1/max(rsum[m],eps) -> f32 store (out).
template <int EPI, int AF32, int NTLOG>
__global__ __launch_bounds__(256, 2)
void gemm_bt(const void* __restrict__ Aall, const u16* __restrict__ Btall,
             void* __restrict__ Call, float* __restrict__ rsum,
             int M, int N, int K) {
    __shared__ u16 As[2][128 * BK];   // 2 x 16KB
    __shared__ u16 Bs[2][128 * BK];   // total 64KB -> 2 blocks/CU

    int h = blockIdx.x;
    int b = h & 7;
    int j = h >> 3;
    int mBase = (j >> NTLOG) * 128;
    int nBase = (j & ((1 << NTLOG) - 1)) * 128;

    const u16*   A16 = (const u16*)Aall + (size_t)b * M * K;    // AF32==0
    const float* A32 = (const float*)Aall + (size_t)b * M * K;  // AF32==1
    const u16* Bt = Btall + (size_t)b * N * K;
    int tid  = threadIdx.x;
    int lane = tid & 63, wid = tid >> 6;
    int wm = wid >> 1, wn = wid & 1;
    int lr = lane & 15, lg = lane >> 4;

    f32x4 acc[4][4] = {};

    // staging geometry: slots s = r*256 + tid; row = r*32 + (tid>>3),
    // chunk-in-row c' = s&7; swizzled position cw = c' ^ (row&7).
    int sRow = tid >> 3;
    int sC   = tid & 7;
    int cw   = sC ^ (sRow & 7);
    const u16* aSrc = A16 + (size_t)(mBase + sRow) * K + cw * 8;  // pre-swizzled src
    const u16* bSrc = Bt  + (size_t)(nBase + sRow) * K + cw * 8;

    auto stageB = [&](int buf, int kt) {
#pragma unroll
        for (int r = 0; r < 4; ++r)
            GLD16(bSrc + (size_t)r * 32 * K + kt, &Bs[buf][(r * 256 + wid * 64) * 8]);
    };
    auto stageA16 = [&](int buf, int kt) {
#pragma unroll
        for (int r = 0; r < 4; ++r)
            GLD16(aSrc + (size_t)r * 32 * K + kt, &As[buf][(r * 256 + wid * 64) * 8]);
    };
    auto loadA32 = [&](int kt, float4* alo, float4* ahi) {
#pragma unroll
        for (int r = 0; r < 4; ++r) {
            const float* g = A32 + (size_t)(mBase + r * 32 + sRow) * K + kt + sC * 8;
            alo[r] = *(const float4*)g;
            ahi[r] = *(const float4*)(g + 4);
        }
    };
    auto writeA32 = [&](int buf, const float4* alo, const float4* ahi) {
#pragma unroll
        for (int r = 0; r < 4; ++r) {
            union { u16 us[8]; uint4 v; } o;
            o.us[0] = f2b(alo[r].x); o.us[1] = f2b(alo[r].y);
            o.us[2] = f2b(alo[r].z); o.us[3] = f2b(alo[r].w);
            o.us[4] = f2b(ahi[r].x); o.us[5] = f2b(ahi[r].y);
            o.us[6] = f2b(ahi[r].z); o.us[7] = f2b(ahi[r].w);
            *(uint4*)&As[buf][(r * 32 + sRow) * 64 + cw * 8] = o.v;
        }
    };
    auto compute = [&](int buf) {
#pragma unroll
        for (int ks = 0; ks < 2; ++ks) {
            bf16x8 af[4], bfr[4];
#pragma unroll
            for (int mi = 0; mi < 4; ++mi) {
                int row = wm * 64 + mi * 16 + lr;
                int cq  = (ks * 4 + lg) ^ (lr & 7);
                af[mi] = *(const bf16x8*)&As[buf][row * 64 + cq * 8];
            }
#pragma unroll
            for (int ni = 0; ni < 4; ++ni) {
                int row = wn * 64 + ni * 16 + lr;
                int cq  = (ks * 4 + lg) ^ (lr & 7);
                bfr[ni] = *(const bf16x8*)&Bs[buf][row * 64 + cq * 8];
            }
#pragma unroll
            for (int mi = 0; mi < 4; ++mi)
#pragma unroll
                for (int ni = 0; ni < 4; ++ni)
                    acc[mi][ni] = __builtin_amdgcn_mfma_f32_16x16x32_bf16(
                        af[mi], bfr[ni], acc[mi][ni], 0, 0, 0);
        }
    };

    int nIter = K / BK;
    // prologue: stage tile 0 into buffer 0
    {
        float4 alo[4], ahi[4];
        if (AF32) { loadA32(0, alo, ahi); writeA32(0, alo, ahi); }
        else      { stageA16(0, 0); }
        stageB(0, 0);
    }
    __syncthreads();   // drains vmcnt+lgkmcnt: tile 0 ready

    for (int t = 0; t < nIter; ++t) {
        int cur = t & 1, nxt = cur ^ 1;
        float4 alo[4], ahi[4];
        bool hn = (t + 1 < nIter);
        if (hn) {                       // issue-early: next tile's loads in flight
            if (AF32) loadA32((t + 1) * BK, alo, ahi);
            else      stageA16(nxt, (t + 1) * BK);
            stageB(nxt, (t + 1) * BK);
        }
        compute(cur);                   // MFMA on current tile hides load latency
        if (AF32 && hn) writeA32(nxt, alo, ahi);  // vmcnt wait lands after MFMAs
        __syncthreads();                // vmcnt(0)+lgkmcnt(0): next tile ready,
                                        // all reads of cur done (safe to reuse)
    }

    int mw = mBase + wm * 64, nw = nBase + wn * 64;
    if (EPI == 0) {
        u16* C = (u16*)Call + (size_t)b * M * N;
#pragma unroll
        for (int mi = 0; mi < 4; ++mi)
#pragma unroll
            for (int r = 0; r < 4; ++r) {
                int m = mw + mi * 16 + lg * 4 + r;
                float vals[4];
                float s = 0.f;
#pragma unroll
                for (int ni = 0; ni < 4; ++ni) {
                    vals[ni] = fmaxf(acc[mi][ni][r], 0.f);
                    s += vals[ni];
                }
#pragma unroll
                for (int ni = 0; ni < 4; ++ni)
                    C[(size_t)m * N + nw + ni * 16 + lr] = f2b(vals[ni]);
                // reduce across the 16 lr-lanes (same lg => same m)
                s += __shfl_xor(s, 1, 64);
                s += __shfl_xor(s, 2, 64);
                s += __shfl_xor(s, 4, 64);
                s += __shfl_xor(s, 8, 64);
                if (lr == 0) atomicAdd(&rsum[(size_t)b * M + m], s);
            }
    } else {
        float* C = (float*)Call + (size_t)b * M * N;
        const float* rs = rsum + (size_t)b * M;
#pragma unroll
        for (int mi = 0; mi < 4; ++mi)
#pragma unroll
            for (int r = 0; r < 4; ++r) {
                int m = mw + mi * 16 + lg * 4 + r;
                float inv = 1.f / fmaxf(rs[m], EPS);
#pragma unroll
                for (int ni = 0; ni < 4; ++ni)
                    C[(size_t)m * N + nw + ni * 16 + lr] = acc[mi][ni][r] * inv;
            }
    }
}

extern "C" void kernel_launch(void* const* d_in, const int* in_sizes, int n_in,
                              void* d_out, int out_size, void* d_ws, size_t ws_size,
                              hipStream_t stream) {
    const float* qz    = (const float*)d_in[0];
    const int*   attr  = (const int*)d_in[1];
    const float* Wbase = (const float*)d_in[2];
    const float* emb   = (const float*)d_in[3];
    const float* Wu    = (const float*)d_in[4];
    const float* Wv    = (const float*)d_in[5];
    float* out = (float*)d_out;

    // workspace carve-up (all 256B aligned)
    char* ws = (char*)d_ws;
    size_t off = 0;
    auto alloc = [&](size_t bytes) -> void* {
        void* p = ws + off;
        off = (off + bytes + 255) & ~(size_t)255;
        return p;
    };
    float* u    = (float*)alloc((size_t)BATCH * DIM_G * 4);
    float* v    = (float*)alloc((size_t)BATCH * DIM_Z * 4);
    float* rsum = (float*)alloc((size_t)BATCH * MROWS * 4);
    u16*   W    = (u16*)  alloc((size_t)BATCH * DIM_G * DIM_Z * 2);
    u16*   WT   = (u16*)  alloc((size_t)BATCH * DIM_G * DIM_Z * 2);
    u16*   qg   = (u16*)  alloc((size_t)BATCH * MROWS * DIM_G * 2);
    if (off > ws_size) return;  // fail loudly (zero output) rather than corrupt

    uv_kernel<<<dim3(6, BATCH), dim3(256), 0, stream>>>(emb, attr, Wu, Wv, u, v, rsum);

    wpack_kernel<<<dim3(4096), dim3(32, 8), 0, stream>>>(Wbase, u, v, W, WT);

    // GEMM1 (fused cast): qg = relu(qz_f32 @ W^T), rsum accumulated in epilogue
    // grid: 8 nT * 16 mT * 8 b = 1024 blocks, XCD-decoded in-kernel
    gemm_bt<0, 1, 3><<<dim3(1024), dim3(256), 0, stream>>>(
        qz, W, qg, rsum, MROWS, DIM_G, DIM_Z);

    // GEMM2: out = (qg @ WT^T) / max(rsum,eps)   (4 nT * 16 mT * 8 b = 512 blocks)
    gemm_bt<1, 0, 2><<<dim3(512), dim3(256), 0, stream>>>(
        qg, WT, out, rsum, MROWS, DIM_Z, DIM_G);
}